// Round 5
// baseline (958.991 us; speedup 1.0000x reference)
//
#include <hip/hip_runtime.h>
#include <cstddef>

#define NA 200000
#define NE 3200000
#define NB 512
#define CAP 48   // padded CSR row capacity; P(deg>=48)~8e-11 per node (lambda=16)

// ---------------- init: cnt=0, g(maxpool acc)=0 ----------------
__global__ void k_init(int* cnt, unsigned* g) {
    int i = blockIdx.x * blockDim.x + threadIdx.x;
    if (i < NA) cnt[i] = 0;
    if (i < NB * 16) g[i] = 0u;
}

// ---------------- conv1d(k=8,VALID)+bias+relu+maxpool3 device body ---------
template<int CIN, int COUT, int OBLK, int LIN, int PITCH, int POUT, int NTT, bool TRANSPOSE>
__device__ __forceinline__ void dev_conv(int b, int oy,
        const float* __restrict__ in, const float* __restrict__ Kw,
        const float* __restrict__ bias, float* __restrict__ out) {
    constexpr int SPO = 256 / OBLK;
    constexpr int PT = (NTT < 4) ? NTT : 4;
    constexpr int NPASS = (NTT + PT - 1) / PT;
    __shared__ __align__(16) float s_in[CIN * PITCH];
    for (int idx = threadIdx.x; idx < CIN * PITCH; idx += 256) s_in[idx] = 0.f;
    __syncthreads();
    if (TRANSPOSE) {
        for (int idx = threadIdx.x; idx < LIN * CIN; idx += 256) {
            int p = idx / CIN, c = idx - p * CIN;
            s_in[c * PITCH + p] = in[(size_t)b * (LIN * CIN) + idx];
        }
    } else {
        for (int idx = threadIdx.x; idx < CIN * LIN; idx += 256) {
            int c = idx / LIN, p = idx - c * LIN;
            s_in[c * PITCH + p] = in[(size_t)b * (CIN * LIN) + idx];
        }
    }
    __syncthreads();
    int ol = threadIdx.x / SPO;
    int s  = threadIdx.x - ol * SPO;
    int o  = oy * OBLK + ol;
    float bo = bias[o];
    const float* wrow = Kw + (size_t)o * CIN * 8;
    for (int pass = 0; pass < NPASS; pass++) {
        float acc[PT][12];
#pragma unroll
        for (int tt = 0; tt < PT; tt++)
#pragma unroll
            for (int j = 0; j < 12; j++) acc[tt][j] = 0.f;
        bool vld[PT]; int tgs[PT];
#pragma unroll
        for (int tt = 0; tt < PT; tt++) {
            int ta = pass * PT + tt;
            int tg = s + SPO * ta;
            tgs[tt] = tg;
            vld[tt] = (ta < NTT) && (4 * tg < POUT);
        }
        for (int i = 0; i < CIN; i++) {
            float wa[8];
            const float4* wp = (const float4*)(wrow + (size_t)i * 8);
            *(float4*)&wa[0] = wp[0];
            *(float4*)&wa[4] = wp[1];
#pragma unroll
            for (int tt = 0; tt < PT; tt++) {
                if (vld[tt]) {
                    const float4* xr = (const float4*)&s_in[i * PITCH + 12 * tgs[tt]];
                    float xa[20];
#pragma unroll
                    for (int q = 0; q < 5; q++) *(float4*)&xa[4 * q] = xr[q];
#pragma unroll
                    for (int j = 0; j < 12; j++) {
                        float sm = acc[tt][j];
#pragma unroll
                        for (int k = 0; k < 8; k++) sm = fmaf(xa[j + k], wa[k], sm);
                        acc[tt][j] = sm;
                    }
                }
            }
        }
#pragma unroll
        for (int tt = 0; tt < PT; tt++) {
            if (vld[tt]) {
#pragma unroll
                for (int p = 0; p < 4; p++) {
                    int P = 4 * tgs[tt] + p;
                    if (P < POUT) {
                        float m = fmaxf(fmaxf(acc[tt][3 * p], acc[tt][3 * p + 1]), acc[tt][3 * p + 2]);
                        out[((size_t)b * COUT + o) * POUT + P] = fmaxf(m + bo, 0.f);
                    }
                }
            }
        }
    }
}

// ---------------- K_A: padded CSR build (atomic-bound) || conv1 ------------
__global__ __launch_bounds__(256) void k_fused_A(
        const int* __restrict__ src, const int* __restrict__ dst,
        int* __restrict__ cnt, int* __restrict__ csr,
        const float* __restrict__ tgt, const float* __restrict__ K1,
        const float* __restrict__ cb1, float* __restrict__ pool1) {
    int bx = blockIdx.x;
    if (bx < 1024) {
        dev_conv<5, 32, 16, 1000, 1008, 331, 6, true>(bx & 511, bx >> 9, tgt, K1, cb1, pool1);
        return;
    }
    int e = (bx - 1024) * 256 + threadIdx.x;
    if (e >= NE) return;
    int s = src[e], d = dst[e];
    int pos = atomicAdd(&cnt[d], 1);
    if (pos < CAP) csr[(size_t)d * CAP + pos] = s;
}

// ---------------- transform1: ht1 = dis * (x @ W1), dis inline -------------
__global__ __launch_bounds__(256) void k_transform1(
        const float* __restrict__ x, const float* __restrict__ W1,
        const int* __restrict__ cnt, float* __restrict__ ht1) {
    __shared__ float sW[16];
    if (threadIdx.x < 16) sW[threadIdx.x] = W1[threadIdx.x];
    __syncthreads();
    int i = blockIdx.x * 256 + threadIdx.x;
    if (i >= NA) return;
    float4 p = ((const float4*)x)[i];
    float dv = rsqrtf((float)cnt[i] + 1.0f);
    float o[4];
#pragma unroll
    for (int f = 0; f < 4; f++)
        o[f] = dv * (p.x * sW[0 * 4 + f] + p.y * sW[1 * 4 + f] +
                     p.z * sW[2 * 4 + f] + p.w * sW[3 * 4 + f]);
    ((float4*)ht1)[i] = make_float4(o[0], o[1], o[2], o[3]);
}

// -------- K_B: (gather1 + transform2 fused) || conv2 -----------------------
// gather: out1 = relu(dv*(sum ht1[src] + ht1[n]) + b1); ht2 = dv*(out1 @ W2)
__global__ __launch_bounds__(256) void k_fused_B(
        const float* __restrict__ pool1, const float* __restrict__ K2,
        const float* __restrict__ cb2, float* __restrict__ pool2,
        const float* __restrict__ ht1, const int* __restrict__ cnt,
        const int* __restrict__ csr, const float* __restrict__ b1,
        const float* __restrict__ W2, float* __restrict__ ht2) {
    int bx = blockIdx.x;
    if (bx < 1024) {
        dev_conv<32, 64, 32, 331, 336, 108, 4, false>(bx & 511, bx >> 9, pool1, K2, cb2, pool2);
        return;
    }
    __shared__ float sW2[32];
    if (threadIdx.x < 32) sW2[threadIdx.x] = W2[threadIdx.x];
    __syncthreads();
    int n = (bx - 1024) * 256 + threadIdx.x;
    if (n >= NA) return;
    int cn0 = cnt[n];
    float dv = rsqrtf((float)cn0 + 1.0f);
    int cn = cn0 > CAP ? CAP : cn0;
    const float4* hq = (const float4*)ht1;
    float4 acc = hq[n];
    const int* row = csr + (size_t)n * CAP;
    const int4* row4 = (const int4*)row;
    int nv = cn >> 2;
    for (int i4 = 0; i4 < nv; i4++) {
        int4 p = row4[i4];
        float4 v0 = hq[p.x], v1 = hq[p.y], v2 = hq[p.z], v3 = hq[p.w];
        acc.x += v0.x + v1.x + v2.x + v3.x;
        acc.y += v0.y + v1.y + v2.y + v3.y;
        acc.z += v0.z + v1.z + v2.z + v3.z;
        acc.w += v0.w + v1.w + v2.w + v3.w;
    }
    for (int e = nv << 2; e < cn; e++) {
        float4 v = hq[row[e]];
        acc.x += v.x; acc.y += v.y; acc.z += v.z; acc.w += v.w;
    }
    const float4 bq = *(const float4*)b1;
    float r[4];
    r[0] = fmaxf(fmaf(dv, acc.x, bq.x), 0.f);
    r[1] = fmaxf(fmaf(dv, acc.y, bq.y), 0.f);
    r[2] = fmaxf(fmaf(dv, acc.z, bq.z), 0.f);
    r[3] = fmaxf(fmaf(dv, acc.w, bq.w), 0.f);
    float o[8];
#pragma unroll
    for (int f = 0; f < 8; f++) {
        float s = 0.f;
#pragma unroll
        for (int k = 0; k < 4; k++) s = fmaf(r[k], sW2[k * 8 + f], s);
        o[f] = dv * s;
    }
    *(float4*)(ht2 + (size_t)n * 8)     = make_float4(o[0], o[1], o[2], o[3]);
    *(float4*)(ht2 + (size_t)n * 8 + 4) = make_float4(o[4], o[5], o[6], o[7]);
}

// -------- K_C: (gather2 + transform3 fused) || conv3 -----------------------
__global__ __launch_bounds__(256) void k_fused_C(
        const float* __restrict__ pool2, const float* __restrict__ K3,
        const float* __restrict__ cb3, float* __restrict__ pool3,
        const float* __restrict__ ht2, const int* __restrict__ cnt,
        const int* __restrict__ csr, const float* __restrict__ b2,
        const float* __restrict__ W3, float* __restrict__ ht3) {
    int bx = blockIdx.x;
    if (bx < 1024) {
        dev_conv<64, 128, 64, 108, 120, 33, 3, false>(bx & 511, bx >> 9, pool2, K3, cb3, pool3);
        return;
    }
    __shared__ float sW3[128];
    if (threadIdx.x < 128) sW3[threadIdx.x] = W3[threadIdx.x];
    __syncthreads();
    int t = (bx - 1024) * 256 + threadIdx.x;
    int n = t >> 1, q = t & 1;
    if (n >= NA) return;
    int cn0 = cnt[n];
    float dv = rsqrtf((float)cn0 + 1.0f);
    int cn = cn0 > CAP ? CAP : cn0;
    const float4* hq = (const float4*)ht2;   // QPN=2
    float4 acc = hq[(size_t)n * 2 + q];
    const int* row = csr + (size_t)n * CAP;
    const int4* row4 = (const int4*)row;
    int nv = cn >> 2;
    for (int i4 = 0; i4 < nv; i4++) {
        int4 p = row4[i4];
        float4 v0 = hq[(size_t)p.x * 2 + q], v1 = hq[(size_t)p.y * 2 + q];
        float4 v2 = hq[(size_t)p.z * 2 + q], v3 = hq[(size_t)p.w * 2 + q];
        acc.x += v0.x + v1.x + v2.x + v3.x;
        acc.y += v0.y + v1.y + v2.y + v3.y;
        acc.z += v0.z + v1.z + v2.z + v3.z;
        acc.w += v0.w + v1.w + v2.w + v3.w;
    }
    for (int e = nv << 2; e < cn; e++) {
        float4 v = hq[(size_t)row[e] * 2 + q];
        acc.x += v.x; acc.y += v.y; acc.z += v.z; acc.w += v.w;
    }
    const float4 bq = *(const float4*)(b2 + q * 4);
    float r[4];
    r[0] = fmaxf(fmaf(dv, acc.x, bq.x), 0.f);
    r[1] = fmaxf(fmaf(dv, acc.y, bq.y), 0.f);
    r[2] = fmaxf(fmaf(dv, acc.z, bq.z), 0.f);
    r[3] = fmaxf(fmaf(dv, acc.w, bq.w), 0.f);
    float other[4];
#pragma unroll
    for (int j = 0; j < 4; j++) other[j] = __shfl_xor(r[j], 1, 64);
    float rf[8];
    if (q == 0) {
#pragma unroll
        for (int j = 0; j < 4; j++) { rf[j] = r[j]; rf[4 + j] = other[j]; }
    } else {
#pragma unroll
        for (int j = 0; j < 4; j++) { rf[j] = other[j]; rf[4 + j] = r[j]; }
    }
    float o[8];
#pragma unroll
    for (int f = 0; f < 8; f++) {
        float s = 0.f;
#pragma unroll
        for (int k = 0; k < 8; k++) s = fmaf(rf[k], sW3[k * 16 + q * 8 + f], s);
        o[f] = dv * s;
    }
    *(float4*)(ht3 + (size_t)n * 16 + q * 8)     = make_float4(o[0], o[1], o[2], o[3]);
    *(float4*)(ht3 + (size_t)n * 16 + q * 8 + 4) = make_float4(o[4], o[5], o[6], o[7]);
}

// -------- K_D: (gather3 + segment_max fused; h3 never stored) || mean ------
__global__ __launch_bounds__(256) void k_fused_D(
        const float* __restrict__ ht3, const int* __restrict__ cnt,
        const int* __restrict__ csr, const float* __restrict__ b3,
        const int* __restrict__ batch, unsigned* __restrict__ g,
        const float* __restrict__ pool3, float* __restrict__ cvec) {
    int bx = blockIdx.x;
    if (bx >= 3125) {                      // mean role
        int idx = (bx - 3125) * 256 + threadIdx.x;
        if (idx < NB * 128) {
            const float* r = pool3 + (size_t)idx * 33;
            float s = 0.f;
#pragma unroll
            for (int p = 0; p < 33; p++) s += r[p];
            cvec[idx] = s * (1.f / 33.f);
        }
        return;
    }
    // gather3 + segmax: 64 nodes/block (spans <= 2 graphs since >=390 nodes/graph)
    __shared__ unsigned sg[32];
    __shared__ int sbmin;
    if (threadIdx.x < 32) sg[threadIdx.x] = 0u;
    if (threadIdx.x == 0) sbmin = batch[bx * 64];
    __syncthreads();
    int t = bx * 256 + threadIdx.x;        // 3125*256 == NA*4 exactly
    int n = t >> 2, q = t & 3;
    int cn0 = cnt[n];
    float dv = rsqrtf((float)cn0 + 1.0f);
    int cn = cn0 > CAP ? CAP : cn0;
    const float4* hq = (const float4*)ht3; // QPN=4
    float4 acc = hq[(size_t)n * 4 + q];
    const int* row = csr + (size_t)n * CAP;
    const int4* row4 = (const int4*)row;
    int nv = cn >> 2;
    for (int i4 = 0; i4 < nv; i4++) {
        int4 p = row4[i4];
        float4 v0 = hq[(size_t)p.x * 4 + q], v1 = hq[(size_t)p.y * 4 + q];
        float4 v2 = hq[(size_t)p.z * 4 + q], v3 = hq[(size_t)p.w * 4 + q];
        acc.x += v0.x + v1.x + v2.x + v3.x;
        acc.y += v0.y + v1.y + v2.y + v3.y;
        acc.z += v0.z + v1.z + v2.z + v3.z;
        acc.w += v0.w + v1.w + v2.w + v3.w;
    }
    for (int e = nv << 2; e < cn; e++) {
        float4 v = hq[(size_t)row[e] * 4 + q];
        acc.x += v.x; acc.y += v.y; acc.z += v.z; acc.w += v.w;
    }
    const float4 bq = *(const float4*)(b3 + q * 4);
    float r0 = fmaxf(fmaf(dv, acc.x, bq.x), 0.f);
    float r1 = fmaxf(fmaf(dv, acc.y, bq.y), 0.f);
    float r2 = fmaxf(fmaf(dv, acc.z, bq.z), 0.f);
    float r3 = fmaxf(fmaf(dv, acc.w, bq.w), 0.f);
    int rb = batch[n] - sbmin;
    if (rb > 1) rb = 1;
    atomicMax(&sg[rb * 16 + q * 4 + 0], __float_as_uint(r0));
    atomicMax(&sg[rb * 16 + q * 4 + 1], __float_as_uint(r1));
    atomicMax(&sg[rb * 16 + q * 4 + 2], __float_as_uint(r2));
    atomicMax(&sg[rb * 16 + q * 4 + 3], __float_as_uint(r3));
    __syncthreads();
    if (threadIdx.x < 32) {
        unsigned v = sg[threadIdx.x];
        int rb2 = threadIdx.x >> 4, f = threadIdx.x & 15;
        int bbn = sbmin + rb2;
        if (v != 0u && bbn < NB) atomicMax(&g[bbn * 16 + f], v);
    }
}

// ------- batch-grouped dense: 8 rows share one pass over W -----------------
template<int K, int BGRP, bool RELU>
__global__ __launch_bounds__(256) void k_dense_g(
        const float* __restrict__ A, const float* __restrict__ W,
        const float* __restrict__ bias, float* __restrict__ out, int ncols) {
    __shared__ float sa[BGRP * K];
    int b0 = blockIdx.y * BGRP;
    for (int t = threadIdx.x; t < BGRP * K; t += 256) {
        int gg = t / K, k = t - gg * K;
        sa[t] = A[(size_t)(b0 + gg) * K + k];
    }
    __syncthreads();
    int j = blockIdx.x * 256 + threadIdx.x;
    if (j >= ncols) return;
    float bj = bias[j];
    float acc[BGRP];
#pragma unroll
    for (int gg = 0; gg < BGRP; gg++) acc[gg] = bj;
#pragma unroll 4
    for (int k = 0; k < K; k++) {
        float w = W[(size_t)k * ncols + j];
#pragma unroll
        for (int gg = 0; gg < BGRP; gg++) acc[gg] = fmaf(sa[gg * K + k], w, acc[gg]);
    }
#pragma unroll
    for (int gg = 0; gg < BGRP; gg++) {
        float v = acc[gg];
        if (RELU) v = fmaxf(v, 0.f);
        out[(size_t)(b0 + gg) * ncols + j] = v;
    }
}

// batch-grouped dense with concatenated input [A1 | A2]
template<int KA, int KB2, int BGRP, bool RELU>
__global__ __launch_bounds__(256) void k_dense_cat_g(
        const float* __restrict__ A1, const float* __restrict__ A2,
        const float* __restrict__ W, const float* __restrict__ bias,
        float* __restrict__ out, int ncols) {
    constexpr int K = KA + KB2;
    __shared__ float sa[BGRP * K];
    int b0 = blockIdx.y * BGRP;
    for (int t = threadIdx.x; t < BGRP * K; t += 256) {
        int gg = t / K, k = t - gg * K;
        sa[t] = (k < KA) ? A1[(size_t)(b0 + gg) * KA + k]
                         : A2[(size_t)(b0 + gg) * KB2 + (k - KA)];
    }
    __syncthreads();
    int j = blockIdx.x * 256 + threadIdx.x;
    if (j >= ncols) return;
    float bj = bias[j];
    float acc[BGRP];
#pragma unroll
    for (int gg = 0; gg < BGRP; gg++) acc[gg] = bj;
#pragma unroll 4
    for (int k = 0; k < K; k++) {
        float w = W[(size_t)k * ncols + j];
#pragma unroll
        for (int gg = 0; gg < BGRP; gg++) acc[gg] = fmaf(sa[gg * K + k], w, acc[gg]);
    }
#pragma unroll
    for (int gg = 0; gg < BGRP; gg++) {
        float v = acc[gg];
        if (RELU) v = fmaxf(v, 0.f);
        out[(size_t)(b0 + gg) * ncols + j] = v;
    }
}

// final 512->2 layer
__global__ __launch_bounds__(256) void k_dense_out(
        const float* __restrict__ A, const float* __restrict__ W,
        const float* __restrict__ bias, float* __restrict__ out) {
    int idx = blockIdx.x * 256 + threadIdx.x;
    if (idx >= NB * 2) return;
    int b = idx >> 1, j = idx & 1;
    float s = bias[j];
#pragma unroll 8
    for (int k = 0; k < 512; k++) s = fmaf(A[b * 512 + k], W[k * 2 + j], s);
    out[idx] = s;
}

extern "C" void kernel_launch(void* const* d_in, const int* in_sizes, int n_in,
                              void* d_out, int out_size, void* d_ws, size_t ws_size,
                              hipStream_t stream) {
    (void)in_sizes; (void)n_in; (void)out_size; (void)ws_size;
    const float* x   = (const float*)d_in[0];
    const int*  ei   = (const int*)d_in[1];
    const int*  batch= (const int*)d_in[2];
    const float* tgt = (const float*)d_in[3];
    const float* W1  = (const float*)d_in[4];  const float* b1  = (const float*)d_in[5];
    const float* W2  = (const float*)d_in[6];  const float* b2  = (const float*)d_in[7];
    const float* W3  = (const float*)d_in[8];  const float* b3  = (const float*)d_in[9];
    const float* Wg1 = (const float*)d_in[10]; const float* bg1 = (const float*)d_in[11];
    const float* Wg2 = (const float*)d_in[12]; const float* bg2 = (const float*)d_in[13];
    const float* K1  = (const float*)d_in[14]; const float* cb1 = (const float*)d_in[15];
    const float* K2  = (const float*)d_in[16]; const float* cb2 = (const float*)d_in[17];
    const float* K3  = (const float*)d_in[18]; const float* cb3 = (const float*)d_in[19];
    const float* Wxt = (const float*)d_in[20]; const float* bxt = (const float*)d_in[21];
    const float* Wf1 = (const float*)d_in[22]; const float* bf1 = (const float*)d_in[23];
    const float* Wf2 = (const float*)d_in[24]; const float* bf2 = (const float*)d_in[25];
    const float* Wo  = (const float*)d_in[26]; const float* bo  = (const float*)d_in[27];
    const int* srcp = ei;        // edge_index[0]
    const int* dstp = ei + NE;   // edge_index[1]

    float* ws = (float*)d_ws;
    float* ht2   = ws; ws += (size_t)NA * 8;          // 1.6M
    float* g     = ws; ws += NB * 16;
    float* gp1   = ws; ws += NB * 1024;
    float* gvec  = ws; ws += NB * 128;
    float* pool1 = ws; ws += (size_t)NB * 32 * 331;   // 5.42M
    float* pool2 = ws; ws += (size_t)NB * 64 * 108;   // 3.54M
    float* pool3 = ws; ws += (size_t)NB * 128 * 33;   // 2.16M
    float* cvec  = ws; ws += NB * 128;
    float* cx    = ws; ws += NB * 128;
    float* xf1   = ws; ws += NB * 1024;
    float* xf2   = ws; ws += NB * 512;
    int*   cnt   = (int*)ws; ws += NA;
    int*   csr   = (int*)ws; ws += (size_t)NA * CAP;  // 9.6M ints, own region

    // aliases with disjoint lifetimes:
    // ht1 (0.8M) in pool3: written K_T1, read K_B; pool3 written K_C.
    // ht3 (3.2M) in pool1: written K_C, read K_D; pool1 last read K_B.
    float* ht1 = pool3;
    float* ht3 = pool1;

    dim3 blk(256);
    const int GB_NA = (NA + 255) / 256;   // 782
    const int GB_NE = (NE + 255) / 256;   // 12500

    k_init<<<GB_NA, blk, 0, stream>>>(cnt, (unsigned*)g);
    // K_A: conv1 (1024 blocks) || CSR build (12500 blocks)
    k_fused_A<<<1024 + GB_NE, blk, 0, stream>>>(srcp, dstp, cnt, csr, tgt, K1, cb1, pool1);
    k_transform1<<<GB_NA, blk, 0, stream>>>(x, W1, cnt, ht1);
    // K_B: conv2 || gather1+transform2
    k_fused_B<<<1024 + GB_NA, blk, 0, stream>>>(pool1, K2, cb2, pool2,
                                                ht1, cnt, csr, b1, W2, ht2);
    // K_C: conv3 || gather2+transform3
    k_fused_C<<<1024 + 2 * GB_NA - 1, blk, 0, stream>>>(pool2, K3, cb3, pool3,
                                                        ht2, cnt, csr, b2, W3, ht3);
    // K_D: gather3+segmax (3125) || mean (256)
    k_fused_D<<<3125 + 256, blk, 0, stream>>>(ht3, cnt, csr, b3, batch, (unsigned*)g,
                                              pool3, cvec);

    // dense head (batch-grouped, BGRP=8 -> grid.y = 64)
    k_dense_g<16, 8, true><<<dim3(4, 64), blk, 0, stream>>>((const float*)g, Wg1, bg1, gp1, 1024);
    k_dense_g<128, 8, true><<<dim3(1, 64), blk, 0, stream>>>(cvec, Wxt, bxt, cx, 128);
    k_dense_g<1024, 8, false><<<dim3(1, 64), blk, 0, stream>>>(gp1, Wg2, bg2, gvec, 128);
    k_dense_cat_g<128, 128, 8, true><<<dim3(4, 64), blk, 0, stream>>>(gvec, cx, Wf1, bf1, xf1, 1024);
    k_dense_g<1024, 8, true><<<dim3(2, 64), blk, 0, stream>>>(xf1, Wf2, bf2, xf2, 512);
    k_dense_out<<<4, blk, 0, stream>>>(xf2, Wo, bo, (float*)d_out);
}

// Round 6
// 753.990 us; speedup vs baseline: 1.2719x; 1.2719x over previous
//
#include <hip/hip_runtime.h>
#include <cstddef>

#define NA 200000
#define NE 3200000
#define NB 512
#define NBKT 256          // dst-range buckets
#define BKTN 782          // nodes per bucket (255*782=199410; last bucket 590)
#define BKTCAP 16384      // stage capacity per bucket (exp 12500, sigma ~111)
#define NEPB 3125         // edges per pass-1 block (1024*3125 = NE)

// ---------------- init: g=0, gcursor[b]=b*BKTCAP ----------------
__global__ void k_init(unsigned* g, int* gcursor) {
    int i = blockIdx.x * blockDim.x + threadIdx.x;
    if (i < NB * 16) g[i] = 0u;
    if (i < NBKT) gcursor[i] = i * BKTCAP;
}

// ---- pass 1: bin edges into 256 dst-range buckets (LDS hist, 256 global
// atomics per block), packed payload (dstLocal<<18 | src), src<2^18 ----
__global__ __launch_bounds__(256) void k_pass1(
        const int* __restrict__ src, const int* __restrict__ dst,
        int* __restrict__ gcursor, unsigned* __restrict__ stage) {
    __shared__ int hcnt[NBKT];
    __shared__ int hbase[NBKT];
    int e0 = blockIdx.x * NEPB;
    hcnt[threadIdx.x] = 0;
    __syncthreads();
    for (int i = threadIdx.x; i < NEPB; i += 256) {
        int d = dst[e0 + i];
        atomicAdd(&hcnt[d / BKTN], 1);
    }
    __syncthreads();
    hbase[threadIdx.x] = atomicAdd(&gcursor[threadIdx.x], hcnt[threadIdx.x]);
    hcnt[threadIdx.x] = 0;
    __syncthreads();
    for (int i = threadIdx.x; i < NEPB; i += 256) {
        int d = dst[e0 + i];
        int s = src[e0 + i];
        int bkt = d / BKTN;
        int dloc = d - bkt * BKTN;
        int k = atomicAdd(&hcnt[bkt], 1);
        stage[hbase[bkt] + k] = ((unsigned)dloc << 18) | (unsigned)s;
    }
}

// ---- exclusive scan of per-bucket totals -> bucket start in compact CSR ----
__global__ __launch_bounds__(256) void k_scan256(
        const int* __restrict__ gcursor, int* __restrict__ bstart) {
    __shared__ int s[NBKT];
    int t = threadIdx.x;
    int tot = gcursor[t] - t * BKTCAP;
    s[t] = tot;
    __syncthreads();
#pragma unroll
    for (int off = 1; off < NBKT; off <<= 1) {
        int u = (t >= off) ? s[t - off] : 0;
        __syncthreads();
        s[t] += u;
        __syncthreads();
    }
    bstart[t] = s[t] - tot;   // exclusive
}

// ---- pass 2: per-bucket count + scan + scatter into compact CSR ----
__global__ __launch_bounds__(256) void k_pass2(
        const unsigned* __restrict__ stage, const int* __restrict__ gcursor,
        const int* __restrict__ bstart, int* __restrict__ rowptr,
        int* __restrict__ cnt, int* __restrict__ csr) {
    __shared__ int lcnt[BKTN];
    __shared__ int lpos[BKTN];
    __shared__ int partial[256];
    int bkt = blockIdx.x;
    int n0 = bkt * BKTN;
    int ncnt = (NA - n0 < BKTN) ? (NA - n0) : BKTN;
    int eBeg = bkt * BKTCAP;
    int eCnt = gcursor[bkt] - eBeg;
    int base = bstart[bkt];
    for (int i = threadIdx.x; i < BKTN; i += 256) lcnt[i] = 0;
    __syncthreads();
    for (int i = threadIdx.x; i < eCnt; i += 256)
        atomicAdd(&lcnt[stage[eBeg + i] >> 18], 1);
    __syncthreads();
    // scan: thread t owns nodes [4t, 4t+4)
    int t = threadIdx.x;
    int mysum = 0;
#pragma unroll
    for (int j = 0; j < 4; j++) {
        int node = 4 * t + j;
        if (node < ncnt) mysum += lcnt[node];
    }
    partial[t] = mysum;
    __syncthreads();
#pragma unroll
    for (int off = 1; off < 256; off <<= 1) {
        int u = (t >= off) ? partial[t - off] : 0;
        __syncthreads();
        partial[t] += u;
        __syncthreads();
    }
    int running = partial[t] - mysum;    // exclusive
#pragma unroll
    for (int j = 0; j < 4; j++) {
        int node = 4 * t + j;
        if (node < ncnt) {
            lpos[node] = running;
            rowptr[n0 + node] = base + running;
            cnt[n0 + node] = lcnt[node];
            running += lcnt[node];
        }
    }
    __syncthreads();
    for (int i = threadIdx.x; i < eCnt; i += 256) {
        unsigned v = stage[eBeg + i];
        int dloc = v >> 18;
        int s = v & 0x3FFFF;
        int k = atomicAdd(&lpos[dloc], 1);
        csr[base + k] = s;
    }
}

// ---------------- conv1 device body (untiled, transpose load) --------------
template<int CIN, int COUT, int OBLK, int LIN, int PITCH, int POUT, int NTT>
__device__ __forceinline__ void dev_conv1(int b, int oy,
        const float* __restrict__ in, const float* __restrict__ Kw,
        const float* __restrict__ bias, float* __restrict__ out) {
    constexpr int SPO = 256 / OBLK;
    constexpr int PT = (NTT < 4) ? NTT : 4;
    constexpr int NPASS = (NTT + PT - 1) / PT;
    __shared__ __align__(16) float s_in[CIN * PITCH];
    for (int idx = threadIdx.x; idx < CIN * PITCH; idx += 256) s_in[idx] = 0.f;
    __syncthreads();
    for (int idx = threadIdx.x; idx < LIN * CIN; idx += 256) {
        int p = idx / CIN, c = idx - p * CIN;
        s_in[c * PITCH + p] = in[(size_t)b * (LIN * CIN) + idx];
    }
    __syncthreads();
    int ol = threadIdx.x / SPO;
    int s  = threadIdx.x - ol * SPO;
    int o  = oy * OBLK + ol;
    float bo = bias[o];
    const float* wrow = Kw + (size_t)o * CIN * 8;
    for (int pass = 0; pass < NPASS; pass++) {
        float acc[PT][12];
#pragma unroll
        for (int tt = 0; tt < PT; tt++)
#pragma unroll
            for (int j = 0; j < 12; j++) acc[tt][j] = 0.f;
        bool vld[PT]; int tgs[PT];
#pragma unroll
        for (int tt = 0; tt < PT; tt++) {
            int ta = pass * PT + tt;
            int tg = s + SPO * ta;
            tgs[tt] = tg;
            vld[tt] = (ta < NTT) && (4 * tg < POUT);
        }
        for (int i = 0; i < CIN; i++) {
            float wa[8];
            const float4* wp = (const float4*)(wrow + (size_t)i * 8);
            *(float4*)&wa[0] = wp[0];
            *(float4*)&wa[4] = wp[1];
#pragma unroll
            for (int tt = 0; tt < PT; tt++) {
                if (vld[tt]) {
                    const float4* xr = (const float4*)&s_in[i * PITCH + 12 * tgs[tt]];
                    float xa[20];
#pragma unroll
                    for (int q = 0; q < 5; q++) *(float4*)&xa[4 * q] = xr[q];
#pragma unroll
                    for (int j = 0; j < 12; j++) {
                        float sm = acc[tt][j];
#pragma unroll
                        for (int k = 0; k < 8; k++) sm = fmaf(xa[j + k], wa[k], sm);
                        acc[tt][j] = sm;
                    }
                }
            }
        }
#pragma unroll
        for (int tt = 0; tt < PT; tt++) {
            if (vld[tt]) {
#pragma unroll
                for (int p = 0; p < 4; p++) {
                    int P = 4 * tgs[tt] + p;
                    if (P < POUT) {
                        float m = fmaxf(fmaxf(acc[tt][3 * p], acc[tt][3 * p + 1]), acc[tt][3 * p + 2]);
                        out[((size_t)b * COUT + o) * POUT + P] = fmaxf(m + bo, 0.f);
                    }
                }
            }
        }
    }
}

// ------------- tiled conv device body (seq-axis tiles, small LDS) ----------
template<int CIN, int COUT, int OBLK, int LIN, int PITCH, int TPOOL, int POUT>
__device__ __forceinline__ void dev_conv_t(int b, int oy, int tile,
        const float* __restrict__ in, const float* __restrict__ Kw,
        const float* __restrict__ bias, float* __restrict__ out) {
    constexpr int SPO = 256 / OBLK;
    constexpr int NQ = TPOOL / 4;
    constexpr int NTT = (NQ + SPO - 1) / SPO;
    constexpr int SPAN = 3 * TPOOL + 7;
    __shared__ __align__(16) float s_in[CIN * PITCH];
    int p0 = tile * TPOOL;
    int cbase = 3 * p0;
    for (int idx = threadIdx.x; idx < CIN * PITCH; idx += 256) {
        int c = idx / PITCH, p = idx - c * PITCH;
        int gp = cbase + p;
        float v = 0.f;
        if (p < SPAN && gp < LIN) v = in[((size_t)b * CIN + c) * LIN + gp];
        s_in[idx] = v;
    }
    __syncthreads();
    int ol = threadIdx.x / SPO;
    int s  = threadIdx.x - ol * SPO;
    int o  = oy * OBLK + ol;
    float bo = bias[o];
    const float* wrow = Kw + (size_t)o * CIN * 8;
    float acc[NTT][12];
#pragma unroll
    for (int tt = 0; tt < NTT; tt++)
#pragma unroll
        for (int j = 0; j < 12; j++) acc[tt][j] = 0.f;
    bool vld[NTT]; int qgs[NTT];
#pragma unroll
    for (int tt = 0; tt < NTT; tt++) {
        int qg = s + SPO * tt;
        qgs[tt] = qg;
        vld[tt] = (qg < NQ) && (p0 + 4 * qg < POUT);
    }
    for (int i = 0; i < CIN; i++) {
        float wa[8];
        const float4* wp = (const float4*)(wrow + (size_t)i * 8);
        *(float4*)&wa[0] = wp[0];
        *(float4*)&wa[4] = wp[1];
#pragma unroll
        for (int tt = 0; tt < NTT; tt++) {
            if (vld[tt]) {
                const float4* xr = (const float4*)&s_in[i * PITCH + 12 * qgs[tt]];
                float xa[20];
#pragma unroll
                for (int q = 0; q < 5; q++) *(float4*)&xa[4 * q] = xr[q];
#pragma unroll
                for (int j = 0; j < 12; j++) {
                    float sm = acc[tt][j];
#pragma unroll
                    for (int k = 0; k < 8; k++) sm = fmaf(xa[j + k], wa[k], sm);
                    acc[tt][j] = sm;
                }
            }
        }
    }
#pragma unroll
    for (int tt = 0; tt < NTT; tt++) {
        if (vld[tt]) {
#pragma unroll
            for (int p = 0; p < 4; p++) {
                int P = p0 + 4 * qgs[tt] + p;
                if (P < POUT) {
                    float m = fmaxf(fmaxf(acc[tt][3 * p], acc[tt][3 * p + 1]), acc[tt][3 * p + 2]);
                    out[((size_t)b * COUT + o) * POUT + P] = fmaxf(m + bo, 0.f);
                }
            }
        }
    }
}

// ---------------- transform1: ht1 = dis * (x @ W1) ----------------
__global__ __launch_bounds__(256) void k_transform1(
        const float* __restrict__ x, const float* __restrict__ W1,
        const int* __restrict__ cnt, float* __restrict__ ht1) {
    __shared__ float sW[16];
    if (threadIdx.x < 16) sW[threadIdx.x] = W1[threadIdx.x];
    __syncthreads();
    int i = blockIdx.x * 256 + threadIdx.x;
    if (i >= NA) return;
    float4 p = ((const float4*)x)[i];
    float dv = rsqrtf((float)cnt[i] + 1.0f);
    float o[4];
#pragma unroll
    for (int f = 0; f < 4; f++)
        o[f] = dv * (p.x * sW[0 * 4 + f] + p.y * sW[1 * 4 + f] +
                     p.z * sW[2 * 4 + f] + p.w * sW[3 * 4 + f]);
    ((float4*)ht1)[i] = make_float4(o[0], o[1], o[2], o[3]);
}

// -------- K_B: conv1 (1024 blocks) || gather1+transform2 (782 blocks) ------
__global__ __launch_bounds__(256) void k_fused_B(
        const float* __restrict__ tgt, const float* __restrict__ K1,
        const float* __restrict__ cb1, float* __restrict__ pool1,
        const float* __restrict__ ht1, const int* __restrict__ rowptr,
        const int* __restrict__ cnt, const int* __restrict__ csr,
        const float* __restrict__ b1, const float* __restrict__ W2,
        float* __restrict__ ht2) {
    int bx = blockIdx.x;
    if (bx < 1024) {
        dev_conv1<5, 32, 16, 1000, 1008, 331, 6>(bx & 511, bx >> 9, tgt, K1, cb1, pool1);
        return;
    }
    __shared__ float sW2[32];
    if (threadIdx.x < 32) sW2[threadIdx.x] = W2[threadIdx.x];
    __syncthreads();
    int n = (bx - 1024) * 256 + threadIdx.x;
    if (n >= NA) return;
    int cn = cnt[n];
    float dv = rsqrtf((float)cn + 1.0f);
    int beg = rowptr[n];
    const float4* hq = (const float4*)ht1;
    float4 acc = hq[n];
    const int* row = csr + beg;
    int e = 0;
    for (; e + 3 < cn; e += 4) {
        int i0 = row[e], i1 = row[e + 1], i2 = row[e + 2], i3 = row[e + 3];
        float4 v0 = hq[i0], v1 = hq[i1], v2 = hq[i2], v3 = hq[i3];
        acc.x += v0.x + v1.x + v2.x + v3.x;
        acc.y += v0.y + v1.y + v2.y + v3.y;
        acc.z += v0.z + v1.z + v2.z + v3.z;
        acc.w += v0.w + v1.w + v2.w + v3.w;
    }
    for (; e < cn; e++) {
        float4 v = hq[row[e]];
        acc.x += v.x; acc.y += v.y; acc.z += v.z; acc.w += v.w;
    }
    const float4 bq = *(const float4*)b1;
    float r[4];
    r[0] = fmaxf(fmaf(dv, acc.x, bq.x), 0.f);
    r[1] = fmaxf(fmaf(dv, acc.y, bq.y), 0.f);
    r[2] = fmaxf(fmaf(dv, acc.z, bq.z), 0.f);
    r[3] = fmaxf(fmaf(dv, acc.w, bq.w), 0.f);
    float o[8];
#pragma unroll
    for (int f = 0; f < 8; f++) {
        float s = 0.f;
#pragma unroll
        for (int k = 0; k < 4; k++) s = fmaf(r[k], sW2[k * 8 + f], s);
        o[f] = dv * s;
    }
    *(float4*)(ht2 + (size_t)n * 8)     = make_float4(o[0], o[1], o[2], o[3]);
    *(float4*)(ht2 + (size_t)n * 8 + 4) = make_float4(o[4], o[5], o[6], o[7]);
}

// -------- K_C: conv2 tiled (1536 blocks) || gather2+transform3 (1563) ------
__global__ __launch_bounds__(256) void k_fused_C(
        const float* __restrict__ pool1, const float* __restrict__ K2,
        const float* __restrict__ cb2, float* __restrict__ pool2,
        const float* __restrict__ ht2, const int* __restrict__ rowptr,
        const int* __restrict__ cnt, const int* __restrict__ csr,
        const float* __restrict__ b2, const float* __restrict__ W3,
        float* __restrict__ ht3) {
    int bx = blockIdx.x;
    if (bx < 1536) {
        // CIN=32,COUT=64,OBLK=64,LIN=331,PITCH=116,TPOOL=36,POUT=108; tiles 0..2
        dev_conv_t<32, 64, 64, 331, 116, 36, 108>(bx & 511, 0, bx >> 9, pool1, K2, cb2, pool2);
        return;
    }
    __shared__ float sW3[128];
    if (threadIdx.x < 128) sW3[threadIdx.x] = W3[threadIdx.x];
    __syncthreads();
    int t = (bx - 1536) * 256 + threadIdx.x;
    int n = t >> 1, q = t & 1;
    if (n >= NA) return;
    int cn = cnt[n];
    float dv = rsqrtf((float)cn + 1.0f);
    int beg = rowptr[n];
    const float4* hq = (const float4*)ht2;   // QPN=2
    float4 acc = hq[(size_t)n * 2 + q];
    const int* row = csr + beg;
    int e = 0;
    for (; e + 3 < cn; e += 4) {
        int i0 = row[e], i1 = row[e + 1], i2 = row[e + 2], i3 = row[e + 3];
        float4 v0 = hq[(size_t)i0 * 2 + q], v1 = hq[(size_t)i1 * 2 + q];
        float4 v2 = hq[(size_t)i2 * 2 + q], v3 = hq[(size_t)i3 * 2 + q];
        acc.x += v0.x + v1.x + v2.x + v3.x;
        acc.y += v0.y + v1.y + v2.y + v3.y;
        acc.z += v0.z + v1.z + v2.z + v3.z;
        acc.w += v0.w + v1.w + v2.w + v3.w;
    }
    for (; e < cn; e++) {
        float4 v = hq[(size_t)row[e] * 2 + q];
        acc.x += v.x; acc.y += v.y; acc.z += v.z; acc.w += v.w;
    }
    const float4 bq = *(const float4*)(b2 + q * 4);
    float r[4];
    r[0] = fmaxf(fmaf(dv, acc.x, bq.x), 0.f);
    r[1] = fmaxf(fmaf(dv, acc.y, bq.y), 0.f);
    r[2] = fmaxf(fmaf(dv, acc.z, bq.z), 0.f);
    r[3] = fmaxf(fmaf(dv, acc.w, bq.w), 0.f);
    float other[4];
#pragma unroll
    for (int j = 0; j < 4; j++) other[j] = __shfl_xor(r[j], 1, 64);
    float rf[8];
    if (q == 0) {
#pragma unroll
        for (int j = 0; j < 4; j++) { rf[j] = r[j]; rf[4 + j] = other[j]; }
    } else {
#pragma unroll
        for (int j = 0; j < 4; j++) { rf[j] = other[j]; rf[4 + j] = r[j]; }
    }
    float o[8];
#pragma unroll
    for (int f = 0; f < 8; f++) {
        float s = 0.f;
#pragma unroll
        for (int k = 0; k < 8; k++) s = fmaf(rf[k], sW3[k * 16 + q * 8 + f], s);
        o[f] = dv * s;
    }
    *(float4*)(ht3 + (size_t)n * 16 + q * 8)     = make_float4(o[0], o[1], o[2], o[3]);
    *(float4*)(ht3 + (size_t)n * 16 + q * 8 + 4) = make_float4(o[4], o[5], o[6], o[7]);
}

// -------- K_D: conv3 tiled (1024 blocks) || gather3+segmax (3125) ----------
__global__ __launch_bounds__(256) void k_fused_D(
        const float* __restrict__ pool2, const float* __restrict__ K3,
        const float* __restrict__ cb3, float* __restrict__ pool3,
        const float* __restrict__ ht3, const int* __restrict__ rowptr,
        const int* __restrict__ cnt, const int* __restrict__ csr,
        const float* __restrict__ b3, const int* __restrict__ batch,
        unsigned* __restrict__ g) {
    int bx = blockIdx.x;
    if (bx < 1024) {
        // CIN=64,COUT=128,OBLK=128,LIN=108,PITCH=68,TPOOL=20,POUT=33; tiles 0..1
        dev_conv_t<64, 128, 128, 108, 68, 20, 33>(bx & 511, 0, bx >> 9, pool2, K3, cb3, pool3);
        return;
    }
    __shared__ unsigned sg[32];
    __shared__ int sbmin;
    int gx = bx - 1024;
    if (threadIdx.x < 32) sg[threadIdx.x] = 0u;
    if (threadIdx.x == 0) sbmin = batch[gx * 64];
    __syncthreads();
    int t = gx * 256 + threadIdx.x;        // 3125*256 == NA*4 exactly
    int n = t >> 2, q = t & 3;
    int cn = cnt[n];
    float dv = rsqrtf((float)cn + 1.0f);
    int beg = rowptr[n];
    const float4* hq = (const float4*)ht3; // QPN=4
    float4 acc = hq[(size_t)n * 4 + q];
    const int* row = csr + beg;
    int e = 0;
    for (; e + 3 < cn; e += 4) {
        int i0 = row[e], i1 = row[e + 1], i2 = row[e + 2], i3 = row[e + 3];
        float4 v0 = hq[(size_t)i0 * 4 + q], v1 = hq[(size_t)i1 * 4 + q];
        float4 v2 = hq[(size_t)i2 * 4 + q], v3 = hq[(size_t)i3 * 4 + q];
        acc.x += v0.x + v1.x + v2.x + v3.x;
        acc.y += v0.y + v1.y + v2.y + v3.y;
        acc.z += v0.z + v1.z + v2.z + v3.z;
        acc.w += v0.w + v1.w + v2.w + v3.w;
    }
    for (; e < cn; e++) {
        float4 v = hq[(size_t)row[e] * 4 + q];
        acc.x += v.x; acc.y += v.y; acc.z += v.z; acc.w += v.w;
    }
    const float4 bq = *(const float4*)(b3 + q * 4);
    float r0 = fmaxf(fmaf(dv, acc.x, bq.x), 0.f);
    float r1 = fmaxf(fmaf(dv, acc.y, bq.y), 0.f);
    float r2 = fmaxf(fmaf(dv, acc.z, bq.z), 0.f);
    float r3 = fmaxf(fmaf(dv, acc.w, bq.w), 0.f);
    int rb = batch[n] - sbmin;
    if (rb > 1) rb = 1;
    atomicMax(&sg[rb * 16 + q * 4 + 0], __float_as_uint(r0));
    atomicMax(&sg[rb * 16 + q * 4 + 1], __float_as_uint(r1));
    atomicMax(&sg[rb * 16 + q * 4 + 2], __float_as_uint(r2));
    atomicMax(&sg[rb * 16 + q * 4 + 3], __float_as_uint(r3));
    __syncthreads();
    if (threadIdx.x < 32) {
        unsigned v = sg[threadIdx.x];
        int rb2 = threadIdx.x >> 4, f = threadIdx.x & 15;
        int bbn = sbmin + rb2;
        if (v != 0u && bbn < NB) atomicMax(&g[bbn * 16 + f], v);
    }
}

// ------- batch-grouped dense: BGRP rows share one pass over W --------------
template<int K, int BGRP, bool RELU>
__global__ __launch_bounds__(256) void k_dense_g(
        const float* __restrict__ A, const float* __restrict__ W,
        const float* __restrict__ bias, float* __restrict__ out, int ncols) {
    __shared__ float sa[BGRP * K];
    int b0 = blockIdx.y * BGRP;
    for (int t = threadIdx.x; t < BGRP * K; t += 256) {
        int gg = t / K, k = t - gg * K;
        sa[t] = A[(size_t)(b0 + gg) * K + k];
    }
    __syncthreads();
    int j = blockIdx.x * 256 + threadIdx.x;
    if (j >= ncols) return;
    float bj = bias[j];
    float acc[BGRP];
#pragma unroll
    for (int gg = 0; gg < BGRP; gg++) acc[gg] = bj;
#pragma unroll 4
    for (int k = 0; k < K; k++) {
        float w = W[(size_t)k * ncols + j];
#pragma unroll
        for (int gg = 0; gg < BGRP; gg++) acc[gg] = fmaf(sa[gg * K + k], w, acc[gg]);
    }
#pragma unroll
    for (int gg = 0; gg < BGRP; gg++) {
        float v = acc[gg];
        if (RELU) v = fmaxf(v, 0.f);
        out[(size_t)(b0 + gg) * ncols + j] = v;
    }
}

// dense with concatenated input [A1 | A2]
template<int KA, int KB2, int BGRP, bool RELU>
__global__ __launch_bounds__(256) void k_dense_cat_g(
        const float* __restrict__ A1, const float* __restrict__ A2,
        const float* __restrict__ W, const float* __restrict__ bias,
        float* __restrict__ out, int ncols) {
    constexpr int K = KA + KB2;
    __shared__ float sa[BGRP * K];
    int b0 = blockIdx.y * BGRP;
    for (int t = threadIdx.x; t < BGRP * K; t += 256) {
        int gg = t / K, k = t - gg * K;
        sa[t] = (k < KA) ? A1[(size_t)(b0 + gg) * KA + k]
                         : A2[(size_t)(b0 + gg) * KB2 + (k - KA)];
    }
    __syncthreads();
    int j = blockIdx.x * 256 + threadIdx.x;
    if (j >= ncols) return;
    float bj = bias[j];
    float acc[BGRP];
#pragma unroll
    for (int gg = 0; gg < BGRP; gg++) acc[gg] = bj;
#pragma unroll 4
    for (int k = 0; k < K; k++) {
        float w = W[(size_t)k * ncols + j];
#pragma unroll
        for (int gg = 0; gg < BGRP; gg++) acc[gg] = fmaf(sa[gg * K + k], w, acc[gg]);
    }
#pragma unroll
    for (int gg = 0; gg < BGRP; gg++) {
        float v = acc[gg];
        if (RELU) v = fmaxf(v, 0.f);
        out[(size_t)(b0 + gg) * ncols + j] = v;
    }
}

// dense with mean-pooled input: A[b][k] = mean_p pool3[b][k][p] (33 taps)
template<int BGRP>
__global__ __launch_bounds__(256) void k_dense_mean(
        const float* __restrict__ pool3, const float* __restrict__ W,
        const float* __restrict__ bias, float* __restrict__ out) {
    __shared__ float sa[BGRP * 128];
    int b0 = blockIdx.y * BGRP;
    for (int t = threadIdx.x; t < BGRP * 128; t += 256) {
        int gg = t >> 7, k = t & 127;
        const float* r = pool3 + ((size_t)(b0 + gg) * 128 + k) * 33;
        float s = 0.f;
#pragma unroll
        for (int p = 0; p < 33; p++) s += r[p];
        sa[t] = s * (1.f / 33.f);
    }
    __syncthreads();
    int j = threadIdx.x;
    if (j >= 128) return;
    float bj = bias[j];
    float acc[BGRP];
#pragma unroll
    for (int gg = 0; gg < BGRP; gg++) acc[gg] = bj;
#pragma unroll 4
    for (int k = 0; k < 128; k++) {
        float w = W[(size_t)k * 128 + j];
#pragma unroll
        for (int gg = 0; gg < BGRP; gg++) acc[gg] = fmaf(sa[gg * 128 + k], w, acc[gg]);
    }
#pragma unroll
    for (int gg = 0; gg < BGRP; gg++)
        out[(size_t)(b0 + gg) * 128 + j] = fmaxf(acc[gg], 0.f);
}

// final 512->2 layer
__global__ __launch_bounds__(256) void k_dense_out(
        const float* __restrict__ A, const float* __restrict__ W,
        const float* __restrict__ bias, float* __restrict__ out) {
    int idx = blockIdx.x * 256 + threadIdx.x;
    if (idx >= NB * 2) return;
    int b = idx >> 1, j = idx & 1;
    float s = bias[j];
#pragma unroll 8
    for (int k = 0; k < 512; k++) s = fmaf(A[b * 512 + k], W[k * 2 + j], s);
    out[idx] = s;
}

extern "C" void kernel_launch(void* const* d_in, const int* in_sizes, int n_in,
                              void* d_out, int out_size, void* d_ws, size_t ws_size,
                              hipStream_t stream) {
    (void)in_sizes; (void)n_in; (void)out_size; (void)ws_size;
    const float* x   = (const float*)d_in[0];
    const int*  ei   = (const int*)d_in[1];
    const int*  batch= (const int*)d_in[2];
    const float* tgt = (const float*)d_in[3];
    const float* W1  = (const float*)d_in[4];  const float* b1  = (const float*)d_in[5];
    const float* W2  = (const float*)d_in[6];  const float* b2  = (const float*)d_in[7];
    const float* W3  = (const float*)d_in[8];  const float* b3  = (const float*)d_in[9];
    const float* Wg1 = (const float*)d_in[10]; const float* bg1 = (const float*)d_in[11];
    const float* Wg2 = (const float*)d_in[12]; const float* bg2 = (const float*)d_in[13];
    const float* K1  = (const float*)d_in[14]; const float* cb1 = (const float*)d_in[15];
    const float* K2  = (const float*)d_in[16]; const float* cb2 = (const float*)d_in[17];
    const float* K3  = (const float*)d_in[18]; const float* cb3 = (const float*)d_in[19];
    const float* Wxt = (const float*)d_in[20]; const float* bxt = (const float*)d_in[21];
    const float* Wf1 = (const float*)d_in[22]; const float* bf1 = (const float*)d_in[23];
    const float* Wf2 = (const float*)d_in[24]; const float* bf2 = (const float*)d_in[25];
    const float* Wo  = (const float*)d_in[26]; const float* bo  = (const float*)d_in[27];
    const int* srcp = ei;        // edge_index[0]
    const int* dstp = ei + NE;   // edge_index[1]

    float* ws = (float*)d_ws;
    float* ht2   = ws; ws += (size_t)NA * 8;          // 1.6M
    float* ht3   = ws; ws += (size_t)NA * 16;         // 3.2M
    float* g     = ws; ws += NB * 16;
    float* gp1   = ws; ws += NB * 1024;
    float* gvec  = ws; ws += NB * 128;
    float* cx    = ws; ws += NB * 128;
    float* xf1   = ws; ws += NB * 1024;
    float* xf2   = ws; ws += NB * 512;
    float* pool1 = ws; ws += (size_t)NB * 32 * 331;   // 5.42M (stage aliases)
    float* pool2 = ws; ws += (size_t)NB * 64 * 108;   // 3.54M
    float* pool3 = ws; ws += (size_t)NB * 128 * 33;   // 2.16M (ht1 aliases)
    int*   cnt    = (int*)ws; ws += NA;
    int*   rowptr = (int*)ws; ws += NA;
    int*   csr    = (int*)ws; ws += NE;               // compact CSR, 3.2M
    int*   gcursor= (int*)ws; ws += NBKT;
    int*   bstart = (int*)ws; ws += NBKT;

    // aliases (disjoint lifetimes):
    // stage (4.19M u32) in pool1: alive pass1->pass2; pool1 written by conv1 (K_B).
    // ht1 (0.8M) in pool3: written transform1, read K_B; pool3 written conv3 (K_D).
    unsigned* stage = (unsigned*)pool1;
    float*    ht1   = pool3;

    dim3 blk(256);
    const int GB_NA = (NA + 255) / 256;   // 782

    // ---- build: two-phase bucket sort -> compact CSR (262K global atomics) ----
    k_init<<<32, blk, 0, stream>>>((unsigned*)g, gcursor);
    k_pass1<<<1024, blk, 0, stream>>>(srcp, dstp, gcursor, stage);
    k_scan256<<<1, blk, 0, stream>>>(gcursor, bstart);
    k_pass2<<<NBKT, blk, 0, stream>>>(stage, gcursor, bstart, rowptr, cnt, csr);

    k_transform1<<<GB_NA, blk, 0, stream>>>(x, W1, cnt, ht1);
    // K_B: conv1 (1024) || gather1+transform2 (782)
    k_fused_B<<<1024 + GB_NA, blk, 0, stream>>>(tgt, K1, cb1, pool1,
                                                ht1, rowptr, cnt, csr, b1, W2, ht2);
    // K_C: conv2 tiled (1536) || gather2+transform3 (1563)
    k_fused_C<<<1536 + 2 * GB_NA - 1, blk, 0, stream>>>(pool1, K2, cb2, pool2,
                                                        ht2, rowptr, cnt, csr, b2, W3, ht3);
    // K_D: conv3 tiled (1024) || gather3+segmax (3125)
    k_fused_D<<<1024 + 3125, blk, 0, stream>>>(pool2, K3, cb3, pool3,
                                               ht3, rowptr, cnt, csr, b3, batch, (unsigned*)g);

    // dense head (batch-grouped, BGRP=8 -> grid.y = 64)
    k_dense_g<16, 8, true><<<dim3(4, 64), blk, 0, stream>>>((const float*)g, Wg1, bg1, gp1, 1024);
    k_dense_mean<8><<<dim3(1, 64), blk, 0, stream>>>(pool3, Wxt, bxt, cx);
    k_dense_g<1024, 8, false><<<dim3(1, 64), blk, 0, stream>>>(gp1, Wg2, bg2, gvec, 128);
    k_dense_cat_g<128, 128, 8, true><<<dim3(4, 64), blk, 0, stream>>>(gvec, cx, Wf1, bf1, xf1, 1024);
    k_dense_g<1024, 8, true><<<dim3(2, 64), blk, 0, stream>>>(xf1, Wf2, bf2, xf2, 512);
    k_dense_out<<<4, blk, 0, stream>>>(xf2, Wo, bo, (float*)d_out);
}